// Round 4
// baseline (343.097 us; speedup 1.0000x reference)
//
#include <hip/hip_runtime.h>
#include <hip/hip_bf16.h>

// Problem constants
#define B_ 4
#define L_ 4096
#define E_ 1024
#define H_ 16
#define D_ 64
#define N_ 64          // B*H heads
#define D2_ 128        // feature dim 2*D
#define EPS_ 1e-6f
#define CH_ 16         // phase1 L-chunks
#define ANGSC (0.5f * 3.14159265358979f / (float)L_)

typedef short short8 __attribute__((ext_vector_type(8)));
typedef float f32x4 __attribute__((ext_vector_type(4)));
typedef unsigned int u32;
typedef unsigned short u16;

static __device__ __forceinline__ u16 bf16u(float x) {
  union { __hip_bfloat16 h; u16 s; } u;
  u.h = __float2bfloat16(x);
  return u.s;
}
static __device__ __forceinline__ u32 pack2bf(float a, float b) {
  return (u32)bf16u(a) | ((u32)bf16u(b) << 16);
}

// ===========================================================================
// NEW PATH: layout transform -> contiguous MFMA kernels
// ===========================================================================

// ---------------------------------------------------------------------------
// t_kv: stream k,v full rows; emit head-major transposed bf16 tiles:
//   kt[n][lt][64d][16l] = bf16(relu(k)*mask)
//   vs[n][lt][64m][16l] = bf16(v*mask*sin),  vc = ...*cos
// plus bf16 sin/cos tables (b==0 blocks).
// grid: (b, lt16) = 1024 blocks. LDS 16x1028 f32 (pad 4: col reads 2-way free).
// ---------------------------------------------------------------------------
__global__ __launch_bounds__(256, 2) void t_kv(
    const float* __restrict__ k, const float* __restrict__ v,
    const float* __restrict__ mask, u32* __restrict__ kt,
    u32* __restrict__ vs, u32* __restrict__ vc,
    u16* __restrict__ tabs_s, u16* __restrict__ tabs_c) {
  __shared__ float sh[16][1028];
  __shared__ float msk[16], mss[16], msc[16];

  const int bid = blockIdx.x;
  const int b = bid >> 8, lt = bid & 255;
  const int l0 = lt * 16;
  const int t = threadIdx.x;

  if (t < 16) {
    const int gl = l0 + t;
    const float m = mask[b * L_ + gl];
    const float ang = (float)(gl + 1) * ANGSC;
    const float s = __sinf(ang), c = __cosf(ang);
    msk[t] = m; mss[t] = m * s; msc[t] = m * c;
    if (b == 0) { tabs_s[gl] = bf16u(s); tabs_c[gl] = bf16u(c); }
  }
  __syncthreads();

  // ---- stage k (16 rows x 4KB, coalesced 1KB/instr) ----
  {
    const float* kb = k + (size_t)(b * L_ + l0) * E_;
#pragma unroll
    for (int rr = 0; rr < 4; ++rr) {
      const int row = (t >> 6) + rr * 4;
#pragma unroll
      for (int seg = 0; seg < 4; ++seg) {
        const int c4 = (t & 63) + seg * 64;
        *(float4*)&sh[row][c4 * 4] = *(const float4*)(kb + (size_t)row * E_ + c4 * 4);
      }
    }
  }
  __syncthreads();
  // ---- write kt per head: flat u32 = d*8+lw (lw = l/2), thread t -> 2t,2t+1
  {
    const int d = t >> 2, lw = (t & 3) * 2;
#pragma unroll
    for (int h = 0; h < 16; ++h) {
      const int c = h * 64 + d;
      const int la = 2 * lw;
      const float x0 = fmaxf(sh[la][c], 0.f) * msk[la];
      const float x1 = fmaxf(sh[la + 1][c], 0.f) * msk[la + 1];
      const float x2 = fmaxf(sh[la + 2][c], 0.f) * msk[la + 2];
      const float x3 = fmaxf(sh[la + 3][c], 0.f) * msk[la + 3];
      const size_t base = ((size_t)(b * 16 + h) * 256 + lt) * 512;
      uint2 val = { pack2bf(x0, x1), pack2bf(x2, x3) };
      *(uint2*)&kt[base + d * 8 + lw] = val;
    }
  }
  __syncthreads();
  // ---- stage v ----
  {
    const float* vb = v + (size_t)(b * L_ + l0) * E_;
#pragma unroll
    for (int rr = 0; rr < 4; ++rr) {
      const int row = (t >> 6) + rr * 4;
#pragma unroll
      for (int seg = 0; seg < 4; ++seg) {
        const int c4 = (t & 63) + seg * 64;
        *(float4*)&sh[row][c4 * 4] = *(const float4*)(vb + (size_t)row * E_ + c4 * 4);
      }
    }
  }
  __syncthreads();
  // ---- write vs, vc per head ----
  {
    const int m = t >> 2, lw = (t & 3) * 2;
#pragma unroll
    for (int h = 0; h < 16; ++h) {
      const int c = h * 64 + m;
      const int la = 2 * lw;
      const float y0 = sh[la][c], y1 = sh[la + 1][c];
      const float y2 = sh[la + 2][c], y3 = sh[la + 3][c];
      const size_t base = ((size_t)(b * 16 + h) * 256 + lt) * 512;
      uint2 a = { pack2bf(y0 * mss[la], y1 * mss[la + 1]),
                  pack2bf(y2 * mss[la + 2], y3 * mss[la + 3]) };
      uint2 cc = { pack2bf(y0 * msc[la], y1 * msc[la + 1]),
                   pack2bf(y2 * msc[la + 2], y3 * msc[la + 3]) };
      *(uint2*)&vs[base + m * 8 + lw] = a;
      *(uint2*)&vc[base + m * 8 + lw] = cc;
    }
  }
}

// ---------------------------------------------------------------------------
// t_q: stream q; emit q_[n][l][128f] bf16, f = 2d+(0:sin,1:cos). No LDS.
// grid: (b, l-tile16) = 1024 blocks; thread = (l-row, head).
// ---------------------------------------------------------------------------
__global__ __launch_bounds__(256, 4) void t_q(
    const float* __restrict__ q, u32* __restrict__ qo) {
  const int bid = blockIdx.x;
  const int b = bid >> 8, l0 = (bid & 255) * 16;
  const int t = threadIdx.x;
  const int h = t & 15, lr = t >> 4;
  const int l = l0 + lr;

  const float ang = (float)(l + 1) * ANGSC;
  const float s = __sinf(ang), c = __cosf(ang);

  const float* qrow = q + (size_t)(b * L_ + l) * E_ + h * 64;
  u32* qout = qo + ((size_t)(b * 16 + h) * L_ + l) * 64;
#pragma unroll
  for (int i = 0; i < 16; ++i) {
    const float4 qv = *(const float4*)(qrow + i * 4);
    const float x = fmaxf(qv.x, 0.f), y = fmaxf(qv.y, 0.f);
    const float zz = fmaxf(qv.z, 0.f), w = fmaxf(qv.w, 0.f);
    uint4 o = { pack2bf(x * s, x * c), pack2bf(y * s, y * c),
                pack2bf(zz * s, zz * c), pack2bf(w * s, w * c) };
    *(uint4*)&qout[i * 4] = o;
  }
}

// ---------------------------------------------------------------------------
// p1: zero-LDS MFMA. kv_even[d][m] = sum_l kt[d][l]*vs[l][m] (f=2d),
// kv_odd via vc (f=2d+1). ksum via broadcast-row table B-frags.
// grid: (ch, n) = CH_*64 blocks; wave w owns d-tile w.
// All fragment loads are dense 16B/lane from transposed tiles.
// ---------------------------------------------------------------------------
__global__ __launch_bounds__(256, 4) void p1(
    const u16* __restrict__ kt, const u16* __restrict__ vs,
    const u16* __restrict__ vc, const u16* __restrict__ tabs_s,
    const u16* __restrict__ tabs_c,
    float* __restrict__ part_kv, float* __restrict__ part_ks) {
  const int bid = blockIdx.x;
  const int n = bid & 63, ch = bid >> 6;
  const int t = threadIdx.x;
  const int wv = t >> 6, lane = t & 63;
  const int c_lo = lane & 15, quad = lane >> 4;

  const u16* ktn = kt + (size_t)n * (256 * 1024);
  const u16* vsn = vs + (size_t)n * (256 * 1024);
  const u16* vcn = vc + (size_t)n * (256 * 1024);

  f32x4 accE[4], accO[4], aS = (f32x4)0.f, aC = (f32x4)0.f;
#pragma unroll
  for (int i = 0; i < 4; ++i) { accE[i] = (f32x4)0.f; accO[i] = (f32x4)0.f; }

  const int d = wv * 16 + c_lo;
#pragma unroll
  for (int ks = 0; ks < 8; ++ks) {          // K-steps of 32 l
    const int lg = ch * 256 + ks * 32 + quad * 8;  // this lane's l-slice
    const int ltt = lg >> 4, lin = lg & 15;
    const short8 af = *(const short8*)&ktn[((size_t)ltt * 64 + d) * 16 + lin];
    const short8 bs = *(const short8*)&tabs_s[lg];  // broadcast rows
    const short8 bc = *(const short8*)&tabs_c[lg];
    aS = __builtin_amdgcn_mfma_f32_16x16x32_bf16(af, bs, aS, 0, 0, 0);
    aC = __builtin_amdgcn_mfma_f32_16x16x32_bf16(af, bc, aC, 0, 0, 0);
#pragma unroll
    for (int mt = 0; mt < 4; ++mt) {
      const int m = mt * 16 + c_lo;
      const short8 bE = *(const short8*)&vsn[((size_t)ltt * 64 + m) * 16 + lin];
      const short8 bO = *(const short8*)&vcn[((size_t)ltt * 64 + m) * 16 + lin];
      accE[mt] = __builtin_amdgcn_mfma_f32_16x16x32_bf16(af, bE, accE[mt], 0, 0, 0);
      accO[mt] = __builtin_amdgcn_mfma_f32_16x16x32_bf16(af, bO, accO[mt], 0, 0, 0);
    }
  }

  // partials: part_kv[ch][n][f][m], f = 2d+half; C layout row=quad*4+r, col=c_lo
  float* pb = part_kv + ((size_t)(ch * 64 + n)) * (128 * 64);
#pragma unroll
  for (int r = 0; r < 4; ++r) {
    const int dd = wv * 16 + quad * 4 + r;
#pragma unroll
    for (int mt = 0; mt < 4; ++mt) {
      const int m = mt * 16 + c_lo;
      pb[(size_t)(2 * dd) * 64 + m] = accE[mt][r];
      pb[(size_t)(2 * dd + 1) * 64 + m] = accO[mt][r];
    }
    if (c_lo == 0) {
      part_ks[((size_t)(ch * 64 + n)) * 128 + 2 * dd] = aS[r];
      part_ks[((size_t)(ch * 64 + n)) * 128 + 2 * dd + 1] = aC[r];
    }
  }
}

// ---------------------------------------------------------------------------
// reduce: sum CH_ partials per head; emit kvt[n][64m][128f] bf16 (B-operand
// layout for p2, via LDS transpose) and ksb[n][128f] bf16.
// grid: 64 blocks (one per head); 32 f32 accumulators per thread.
// ---------------------------------------------------------------------------
__global__ __launch_bounds__(256) void reduce_k(
    const float* __restrict__ part_kv, const float* __restrict__ part_ks,
    u16* __restrict__ kvt, u16* __restrict__ ksb) {
  __shared__ u16 kvsh[64 * 136];
  const int n = blockIdx.x;
  const int t = threadIdx.x;

  float a[32];
#pragma unroll
  for (int j = 0; j < 32; ++j) a[j] = 0.f;
#pragma unroll
  for (int cc = 0; cc < CH_; ++cc) {
    const float* p = part_kv + ((size_t)(cc * 64 + n)) * 8192 + t * 32;
#pragma unroll
    for (int j = 0; j < 8; ++j) {
      const float4 x = *(const float4*)(p + j * 4);
      a[4 * j] += x.x; a[4 * j + 1] += x.y; a[4 * j + 2] += x.z; a[4 * j + 3] += x.w;
    }
  }
  if (t < 128) {
    float s = 0.f;
#pragma unroll
    for (int cc = 0; cc < CH_; ++cc)
      s += part_ks[((size_t)(cc * 64 + n)) * 128 + t];
    ksb[n * 128 + t] = bf16u(s);
  }
  // flat = f*64 + m; thread span [t*32, t*32+32): f = t>>1, m = (t&1)*32 + j
  const int f = t >> 1, m0 = (t & 1) * 32;
#pragma unroll
  for (int j = 0; j < 32; ++j) kvsh[(m0 + j) * 136 + f] = bf16u(a[j]);
  __syncthreads();
  // write out: thread t -> row m = t>>2, f-range (t&3)*32..+32 (64B)
  const int m = t >> 2, fo = (t & 3) * 32;
  u16* o = kvt + (size_t)n * 8192 + m * 128 + fo;
#pragma unroll
  for (int j = 0; j < 4; ++j)
    *(short8*)(o + j * 8) = *(short8*)&kvsh[m * 136 + fo + j * 8];
}

// ---------------------------------------------------------------------------
// p2: out[l][m] = z * sum_f q_[l][f]*kvt[m][f];  z = 1/max(q_.ksb, eps).
// Zero LDS, no barriers, pure 16B frag loads. grid: 64 heads x 64 l-tiles.
// ---------------------------------------------------------------------------
__global__ __launch_bounds__(256, 4) void p2(
    const u16* __restrict__ qo, const u16* __restrict__ kvt,
    const u16* __restrict__ ksb, float* __restrict__ out) {
  const int bid = blockIdx.x;
  const int n = bid & 63, lt = bid >> 6;
  const int t = threadIdx.x;
  const int wv = t >> 6, lane = t & 63;
  const int c_lo = lane & 15, quad = lane >> 4;
  const int l = lt * 64 + wv * 16 + c_lo;

  const u16* qrow = qo + ((size_t)n * L_ + l) * 128;
  const u16* kvh = kvt + (size_t)n * 8192;
  const u16* ksh = ksb + n * 128;

  f32x4 acc[4], acc5 = (f32x4)0.f;
#pragma unroll
  for (int mt = 0; mt < 4; ++mt) acc[mt] = (f32x4)0.f;

#pragma unroll
  for (int kk = 0; kk < 4; ++kk) {
    const int fo = kk * 32 + quad * 8;
    const short8 af = *(const short8*)&qrow[fo];
#pragma unroll
    for (int mt = 0; mt < 4; ++mt) {
      const short8 bfr = *(const short8*)&kvh[(mt * 16 + c_lo) * 128 + fo];
      acc[mt] = __builtin_amdgcn_mfma_f32_16x16x32_bf16(af, bfr, acc[mt], 0, 0, 0);
    }
    const short8 bks = *(const short8*)&ksh[fo];  // broadcast: all cols = den
    acc5 = __builtin_amdgcn_mfma_f32_16x16x32_bf16(af, bks, acc5, 0, 0, 0);
  }

#pragma unroll
  for (int r = 0; r < 4; ++r) {
    const float zz = 1.f / fmaxf(acc5[r], EPS_);
    const int gl = lt * 64 + wv * 16 + quad * 4 + r;
    float* ob = out + (size_t)n * (L_ * D_) + (size_t)gl * D_;
#pragma unroll
    for (int mt = 0; mt < 4; ++mt) ob[mt * 16 + c_lo] = acc[mt][r] * zz;
  }
}

// ===========================================================================
// FALLBACK PATH (R3 kernels, verified): used if ws too small for new layout
// ===========================================================================
__global__ __launch_bounds__(256, 4) void r3_phase1(
    const float* __restrict__ k, const float* __restrict__ v,
    const float* __restrict__ mask,
    float* __restrict__ part_kv, float* __restrict__ part_ks) {
  __shared__ __align__(16) u16 ka[D2_ * 72];
  __shared__ __align__(16) u16 vt[D_ * 72];
  __shared__ float mm[256], ms[256], mc[256];
  const int bid = blockIdx.x;
  const int n = bid & 63, ch = bid >> 6;
  const int b = n >> 4, h = n & 15;
  const int t = threadIdx.x;
  const int wv = t >> 6, lane = t & 63;
  const int c_lo = lane & 15, lp = lane >> 4;
  const int c = wv * 16 + c_lo;
  {
    const int gl = ch * 256 + t;
    const float m = mask[b * L_ + gl];
    const float ang = (float)(gl + 1) * ANGSC;
    mm[t] = m; ms[t] = m * __sinf(ang); mc[t] = m * __cosf(ang);
  }
  const float* kbase = k + (size_t)(b * L_ + ch * 256) * E_ + h * 64 + c;
  const float* vbase = v + (size_t)(b * L_ + ch * 256) * E_ + h * 64 + c;
  float pk0[8], pk1[8], pv0[8], pv1[8];
#pragma unroll
  for (int i = 0; i < 8; ++i) {
    const int l = 8 * i + 2 * lp;
    pk0[i] = kbase[(size_t)l * E_]; pk1[i] = kbase[(size_t)(l + 1) * E_];
    pv0[i] = vbase[(size_t)l * E_]; pv1[i] = vbase[(size_t)(l + 1) * E_];
  }
  f32x4 acc[2][4];
#pragma unroll
  for (int i = 0; i < 2; ++i)
#pragma unroll
    for (int j = 0; j < 4; ++j) acc[i][j] = (f32x4)0.f;
  float kss = 0.f, ksc = 0.f;
  for (int st = 0; st < 4; ++st) {
    __syncthreads();
#pragma unroll
    for (int i = 0; i < 8; ++i) {
      const int l = 8 * i + 2 * lp, lg = st * 64 + l, li = 4 * i + lp;
      const float kr0 = fmaxf(pk0[i], 0.f), kr1 = fmaxf(pk1[i], 0.f);
      const float a0 = kr0 * ms[lg], a1 = kr1 * ms[lg + 1];
      const float c0 = kr0 * mc[lg], c1 = kr1 * mc[lg + 1];
      ((u32*)ka)[c * 36 + li] = pack2bf(a0, a1);
      ((u32*)ka)[(c + 64) * 36 + li] = pack2bf(c0, c1);
      ((u32*)vt)[c * 36 + li] = pack2bf(pv0[i] * mm[lg], pv1[i] * mm[lg + 1]);
      kss += a0 + a1; ksc += c0 + c1;
    }
    __syncthreads();
    if (st < 3) {
      const int lo = (st + 1) * 64;
#pragma unroll
      for (int i = 0; i < 8; ++i) {
        const int l = lo + 8 * i + 2 * lp;
        pk0[i] = kbase[(size_t)l * E_]; pk1[i] = kbase[(size_t)(l + 1) * E_];
        pv0[i] = vbase[(size_t)l * E_]; pv1[i] = vbase[(size_t)(l + 1) * E_];
      }
    }
#pragma unroll
    for (int kk = 0; kk < 2; ++kk) {
      const int colo = kk * 32 + lp * 8;
      short8 af[2], bfr[4];
#pragma unroll
      for (int dt = 0; dt < 2; ++dt)
        af[dt] = *(const short8*)&ka[(wv * 32 + dt * 16 + c_lo) * 72 + colo];
#pragma unroll
      for (int mt = 0; mt < 4; ++mt)
        bfr[mt] = *(const short8*)&vt[(mt * 16 + c_lo) * 72 + colo];
#pragma unroll
      for (int dt = 0; dt < 2; ++dt)
#pragma unroll
        for (int mt = 0; mt < 4; ++mt)
          acc[dt][mt] = __builtin_amdgcn_mfma_f32_16x16x32_bf16(
              af[dt], bfr[mt], acc[dt][mt], 0, 0, 0);
    }
  }
  const size_t pbase = (size_t)(ch * N_ + n) * (D2_ * D_);
#pragma unroll
  for (int dt = 0; dt < 2; ++dt) {
    const int dd = wv * 32 + dt * 16 + lp * 4;
#pragma unroll
    for (int mt = 0; mt < 4; ++mt) {
      const int mcol = mt * 16 + c_lo;
#pragma unroll
      for (int r = 0; r < 4; ++r)
        part_kv[pbase + (size_t)(dd + r) * D_ + mcol] = acc[dt][mt][r];
    }
  }
  kss += __shfl_xor(kss, 16); kss += __shfl_xor(kss, 32);
  ksc += __shfl_xor(ksc, 16); ksc += __shfl_xor(ksc, 32);
  if (lp == 0) {
    part_ks[(size_t)(ch * N_ + n) * D2_ + c] = kss;
    part_ks[(size_t)(ch * N_ + n) * D2_ + c + 64] = ksc;
  }
}

__global__ __launch_bounds__(256) void r3_reduce(
    const float* __restrict__ part_kv, const float* __restrict__ part_ks,
    u16* __restrict__ kvt, u16* __restrict__ ksb) {
  __shared__ float l0s[8][65], l1s[8][65];
  const int n = blockIdx.x & 63, fs = blockIdx.x >> 6;
  const int t = threadIdx.x;
#pragma unroll
  for (int p = 0; p < 4; ++p) {
    const int idx = t + 256 * p;
    const int g = idx >> 9, dd = (idx >> 6) & 7, m = idx & 63;
    const int d = g * 64 + fs * 8 + dd;
    float s = 0.f;
#pragma unroll
    for (int cc = 0; cc < CH_; ++cc)
      s += part_kv[(size_t)(cc * N_ + n) * (D2_ * D_) + d * 64 + m];
    if (g == 0) l0s[dd][m] = s; else l1s[dd][m] = s;
  }
  if (fs == 0 && t < D2_) {
    float s = 0.f;
#pragma unroll
    for (int cc = 0; cc < CH_; ++cc)
      s += part_ks[(size_t)(cc * N_ + n) * D2_ + t];
    ksb[n * D2_ + 2 * (t & 63) + (t >> 6)] = bf16u(s);
  }
  __syncthreads();
  u32* kvt32 = (u32*)(kvt + (size_t)n * (D_ * D2_));
#pragma unroll
  for (int p = 0; p < 2; ++p) {
    const int idx = t + 256 * p;
    const int j = idx & 7, m = idx >> 3;
    kvt32[m * 64 + fs * 8 + j] = pack2bf(l0s[j][m], l1s[j][m]);
  }
}

__global__ __launch_bounds__(256, 4) void r3_phase2(
    const float* __restrict__ q, const u16* __restrict__ kvt,
    const u16* __restrict__ ksb, float* __restrict__ out) {
  const int bid = blockIdx.x;
  const int n = bid & 63, lt = bid >> 6;
  const int b = n >> 4, h = n & 15;
  const int t = threadIdx.x;
  const int wv = t >> 6, lane = t & 63;
  const int c_lo = lane & 15, quad = lane >> 4;
  const int l = lt * 64 + wv * 16 + c_lo;
  const float ang = (float)(l + 1) * ANGSC;
  const float sn = __sinf(ang), cs = __cosf(ang);
  const float* qrow = q + (size_t)(b * L_ + l) * E_ + h * 64;
  short8 af[4];
#pragma unroll
  for (int kk = 0; kk < 4; ++kk) {
    const float4 qv = *(const float4*)(qrow + kk * 16 + quad * 4);
    const float x = fmaxf(qv.x, 0.f), y = fmaxf(qv.y, 0.f);
    const float z2 = fmaxf(qv.z, 0.f), w = fmaxf(qv.w, 0.f);
    short8 a;
    a[0] = (short)bf16u(x * sn); a[1] = (short)bf16u(x * cs);
    a[2] = (short)bf16u(y * sn); a[3] = (short)bf16u(y * cs);
    a[4] = (short)bf16u(z2 * sn); a[5] = (short)bf16u(z2 * cs);
    a[6] = (short)bf16u(w * sn); a[7] = (short)bf16u(w * cs);
    af[kk] = a;
  }
  const u16* kvh = kvt + (size_t)n * (D_ * D2_);
  const u16* ksh = ksb + n * D2_;
  f32x4 acc[4], acc5 = (f32x4)0.f;
#pragma unroll
  for (int mt = 0; mt < 4; ++mt) acc[mt] = (f32x4)0.f;
#pragma unroll
  for (int kk = 0; kk < 4; ++kk) {
    const int fo = kk * 32 + quad * 8;
#pragma unroll
    for (int mt = 0; mt < 4; ++mt) {
      const short8 bfr = *(const short8*)&kvh[(mt * 16 + c_lo) * D2_ + fo];
      acc[mt] = __builtin_amdgcn_mfma_f32_16x16x32_bf16(af[kk], bfr, acc[mt], 0, 0, 0);
    }
    const short8 bks = *(const short8*)&ksh[fo];
    acc5 = __builtin_amdgcn_mfma_f32_16x16x32_bf16(af[kk], bks, acc5, 0, 0, 0);
  }
#pragma unroll
  for (int r = 0; r < 4; ++r) {
    const float den = __shfl(acc5[r], quad * 16);
    const float zz = 1.f / fmaxf(den, EPS_);
    const int gl = lt * 64 + wv * 16 + quad * 4 + r;
    float* ob = out + (size_t)n * (L_ * D_) + (size_t)gl * D_;
#pragma unroll
    for (int mt = 0; mt < 4; ++mt) ob[mt * 16 + c_lo] = acc[mt][r] * zz;
  }
}

// ---------------------------------------------------------------------------
extern "C" void kernel_launch(void* const* d_in, const int* in_sizes, int n_in,
                              void* d_out, int out_size, void* d_ws,
                              size_t ws_size, hipStream_t stream) {
  const float* q = (const float*)d_in[0];
  const float* k = (const float*)d_in[1];
  const float* v = (const float*)d_in[2];
  const float* mask = (const float*)d_in[3];
  float* out = (float*)d_out;
  char* ws = (char*)d_ws;

  // new-path workspace layout (bytes)
  const size_t SZ_KT = 33554432, SZ_VS = 33554432, SZ_VC = 33554432;
  const size_t SZ_PKV = 33554432, SZ_PKS = 524288, SZ_KVT = 1048576;
  const size_t SZ_KSB = 16384, SZ_TAB = 16384;
  const size_t o_kt = 0, o_vs = o_kt + SZ_KT, o_vc = o_vs + SZ_VS;
  const size_t o_pkv = o_vc + SZ_VC, o_pks = o_pkv + SZ_PKV;
  const size_t o_kvt = o_pks + SZ_PKS, o_ksb = o_kvt + SZ_KVT;
  const size_t o_ts = o_ksb + SZ_KSB, o_tc = o_ts + SZ_TAB / 2;
  const size_t need = o_tc + SZ_TAB / 2;

  if (ws_size >= need) {
    u32* kt = (u32*)(ws + o_kt);
    u32* vs = (u32*)(ws + o_vs);
    u32* vc = (u32*)(ws + o_vc);
    float* part_kv = (float*)(ws + o_pkv);
    float* part_ks = (float*)(ws + o_pks);
    u16* kvt = (u16*)(ws + o_kvt);
    u16* ksb = (u16*)(ws + o_ksb);
    u16* tabs_s = (u16*)(ws + o_ts);
    u16* tabs_c = (u16*)(ws + o_tc);
    u32* qo = (u32*)(ws + o_kt);  // q_ overlays kt+vs AFTER p1 consumed them

    t_kv<<<dim3(4 * 256), dim3(256), 0, stream>>>(k, v, mask, kt, vs, vc,
                                                  tabs_s, tabs_c);
    p1<<<dim3(CH_ * 64), dim3(256), 0, stream>>>((u16*)kt, (u16*)vs, (u16*)vc,
                                                 tabs_s, tabs_c, part_kv, part_ks);
    t_q<<<dim3(4 * 256), dim3(256), 0, stream>>>(q, qo);
    reduce_k<<<dim3(64), dim3(256), 0, stream>>>(part_kv, part_ks, kvt, ksb);
    p2<<<dim3(64 * 64), dim3(256), 0, stream>>>((u16*)qo, kvt, ksb, out);
  } else {
    // R3 fallback (fits in ~35 MB)
    float* part_kv = (float*)d_ws;
    float* part_ks = part_kv + (size_t)CH_ * N_ * D2_ * D_;
    u16* kvt = (u16*)(part_ks + (size_t)CH_ * N_ * D2_);
    u16* ksb = kvt + (size_t)N_ * D2_ * D_;
    r3_phase1<<<dim3(CH_ * N_), dim3(256), 0, stream>>>(k, v, mask, part_kv, part_ks);
    r3_reduce<<<dim3(8 * N_), dim3(256), 0, stream>>>(part_kv, part_ks, kvt, ksb);
    r3_phase2<<<dim3(N_ * 64), dim3(256), 0, stream>>>(q, kvt, ksb, out);
  }
}

// Round 5
// 276.650 us; speedup vs baseline: 1.2402x; 1.2402x over previous
//
#include <hip/hip_runtime.h>
#include <hip/hip_bf16.h>

// Problem constants
#define B_ 4
#define L_ 4096
#define E_ 1024
#define H_ 16
#define D_ 64
#define N_ 64          // B*H heads
#define D2_ 128        // feature dim 2*D
#define EPS_ 1e-6f
#define CH_ 16         // phase1 L-chunks
#define ANGSC (0.5f * 3.14159265358979f / (float)L_)

typedef short short8 __attribute__((ext_vector_type(8)));
typedef float f32x4 __attribute__((ext_vector_type(4)));
typedef unsigned int u32;
typedef unsigned short u16;

static __device__ __forceinline__ u16 bf16u(float x) {
  union { __hip_bfloat16 h; u16 s; } u;
  u.h = __float2bfloat16(x);
  return u.s;
}
static __device__ __forceinline__ u32 pack2bf(float a, float b) {
  return (u32)bf16u(a) | ((u32)bf16u(b) << 16);
}

// ---------------------------------------------------------------------------
// p1f: phase1 MFMA with fully-coalesced float4 staging + swizzled LDS
// transpose. partial kv[dr][m] = sum_l k_[l][dr]*v[l][m] (dr<64 sin, >=64
// cos), part_ks[dr] = sum_l k_[l][dr].
// grid: CH_*64 blocks, 256 thr. LDS rows (d-major) stride 40 u32; l-word
// index XOR-swizzled by ((d>>3)&7)<<2 -> ds_write_b32 2-way (free),
// ds_read_b128 16B-aligned.
// ---------------------------------------------------------------------------
__global__ __launch_bounds__(256, 4) void p1f(
    const float* __restrict__ k, const float* __restrict__ v,
    const float* __restrict__ mask,
    float* __restrict__ part_kv, float* __restrict__ part_ks) {
  __shared__ __align__(16) u32 smem[128 * 40 + 64 * 40];  // ka | vt (30720 B)
  __shared__ float mm[256], ms[256], mc[256];
  u32* ka = smem;
  u32* vt = smem + 128 * 40;

  const int bid = blockIdx.x;
  const int n = bid & 63, ch = bid >> 6;
  const int b = n >> 4, h = n & 15;
  const int t = threadIdx.x;
  const int wv = t >> 6, lane = t & 63;
  const int c_lo = lane & 15, quad = lane >> 4;
  const int o4 = t & 15;   // col-quad: this thread packs d = o4*4 + j
  const int ar = t >> 4;   // row-pair 0..15: rows 2ar, 2ar+1 per pass

  // row-constant tables for the whole 256-row chunk
  {
    const int gl = ch * 256 + t;
    const float m = mask[b * L_ + gl];
    const float ang = (float)(gl + 1) * ANGSC;
    mm[t] = m; ms[t] = m * __sinf(ang); mc[t] = m * __cosf(ang);
  }

  const float* kb = k + (size_t)(b * L_ + ch * 256) * E_ + h * 64 + o4 * 4;
  const float* vb = v + (size_t)(b * L_ + ch * 256) * E_ + h * 64 + o4 * 4;

  // prefetch stage 0: per pass p, rows 2ar,2ar+1; 16 lanes x 16B = 256B segs
  float4 pk[4], pv[4];
#pragma unroll
  for (int p = 0; p < 2; ++p)
#pragma unroll
    for (int r = 0; r < 2; ++r) {
      const int row = p * 32 + 2 * ar + r;
      pk[p * 2 + r] = *(const float4*)(kb + (size_t)row * E_);
      pv[p * 2 + r] = *(const float4*)(vb + (size_t)row * E_);
    }

  f32x4 acc[2][4];
#pragma unroll
  for (int i = 0; i < 2; ++i)
#pragma unroll
    for (int j = 0; j < 4; ++j) acc[i][j] = (f32x4)0.f;
  float aS[4] = {0.f, 0.f, 0.f, 0.f}, aC[4] = {0.f, 0.f, 0.f, 0.f};

  const int swz = (o4 >> 1) << 2;  // = ((d>>3)&7)<<2 for d = o4*4+j

  for (int st = 0; st < 4; ++st) {
    __syncthreads();  // stage 0: tables visible; else: prev MFMA reads done
    // pack prefetched regs -> LDS bf16 transposed (l-pairs per u32)
#pragma unroll
    for (int p = 0; p < 2; ++p) {
      const int l0 = st * 64 + p * 32 + 2 * ar;
      const int lwS = (p * 16 + ar) ^ swz;
      const float m0 = mm[l0], m1 = mm[l0 + 1];
      const float s0 = ms[l0], s1 = ms[l0 + 1];
      const float c0 = mc[l0], c1 = mc[l0 + 1];
      const float* k0p = (const float*)&pk[p * 2];
      const float* k1p = (const float*)&pk[p * 2 + 1];
      const float* v0p = (const float*)&pv[p * 2];
      const float* v1p = (const float*)&pv[p * 2 + 1];
#pragma unroll
      for (int j = 0; j < 4; ++j) {
        const int d = o4 * 4 + j;
        const float kr0 = fmaxf(k0p[j], 0.f), kr1 = fmaxf(k1p[j], 0.f);
        const float x0 = kr0 * s0, x1 = kr1 * s1;
        const float y0 = kr0 * c0, y1 = kr1 * c1;
        ka[d * 40 + lwS] = pack2bf(x0, x1);
        ka[(d + 64) * 40 + lwS] = pack2bf(y0, y1);
        vt[d * 40 + lwS] = pack2bf(v0p[j] * m0, v1p[j] * m1);
        aS[j] += x0 + x1;
        aC[j] += y0 + y1;
      }
    }
    __syncthreads();
    // prefetch next stage while MFMA consumes this one
    if (st < 3) {
      const float* kn = kb + (size_t)(st + 1) * 64 * E_;
      const float* vn = vb + (size_t)(st + 1) * 64 * E_;
#pragma unroll
      for (int p = 0; p < 2; ++p)
#pragma unroll
        for (int r = 0; r < 2; ++r) {
          const int row = p * 32 + 2 * ar + r;
          pk[p * 2 + r] = *(const float4*)(kn + (size_t)row * E_);
          pv[p * 2 + r] = *(const float4*)(vn + (size_t)row * E_);
        }
    }
    // MFMA: 2 K-steps of 32 l
#pragma unroll
    for (int kk = 0; kk < 2; ++kk) {
      short8 af[2], bfr[4];
#pragma unroll
      for (int dt = 0; dt < 2; ++dt) {
        const int dr = wv * 32 + dt * 16 + c_lo;
        const int lwr = (kk * 16 + quad * 4) ^ (((dr >> 3) & 7) << 2);
        af[dt] = *(const short8*)&ka[dr * 40 + lwr];
      }
#pragma unroll
      for (int mt = 0; mt < 4; ++mt) {
        const int mr = mt * 16 + c_lo;
        const int lwr = (kk * 16 + quad * 4) ^ (((mr >> 3) & 7) << 2);
        bfr[mt] = *(const short8*)&vt[mr * 40 + lwr];
      }
#pragma unroll
      for (int dt = 0; dt < 2; ++dt)
#pragma unroll
        for (int mt = 0; mt < 4; ++mt)
          acc[dt][mt] = __builtin_amdgcn_mfma_f32_16x16x32_bf16(
              af[dt], bfr[mt], acc[dt][mt], 0, 0, 0);
    }
  }

  // write partial kv (fp32). C layout: row(dr)=quad*4+r, col(m)=c_lo
  const size_t pbase = (size_t)(ch * N_ + n) * (D2_ * D_);
#pragma unroll
  for (int dt = 0; dt < 2; ++dt) {
    const int dd = wv * 32 + dt * 16 + quad * 4;
#pragma unroll
    for (int mt = 0; mt < 4; ++mt) {
      const int mcol = mt * 16 + c_lo;
#pragma unroll
      for (int r = 0; r < 4; ++r)
        part_kv[pbase + (size_t)(dd + r) * D_ + mcol] = acc[dt][mt][r];
    }
  }

  // ksum: per-thread partials -> LDS (reuse smem) -> 128-thread reduce
  __syncthreads();
  float* fks = (float*)smem;  // 128 x 17 (8704 B)
#pragma unroll
  for (int j = 0; j < 4; ++j) {
    fks[(o4 * 4 + j) * 17 + ar] = aS[j];
    fks[(o4 * 4 + j + 64) * 17 + ar] = aC[j];
  }
  __syncthreads();
  if (t < 128) {
    float s = 0.f;
#pragma unroll
    for (int i = 0; i < 16; ++i) s += fks[t * 17 + i];
    part_ks[(size_t)(ch * N_ + n) * D2_ + t] = s;
  }
}

// ---------------------------------------------------------------------------
// r3_reduce (unchanged, verified): sum chunk partials; emit kvt[n][m][f] bf16
// with interleaved f = 2d+half, ksb[n][f] bf16. grid: 64 heads x 8 f-slices.
// ---------------------------------------------------------------------------
__global__ __launch_bounds__(256) void r3_reduce(
    const float* __restrict__ part_kv, const float* __restrict__ part_ks,
    u16* __restrict__ kvt, u16* __restrict__ ksb) {
  __shared__ float l0s[8][65], l1s[8][65];
  const int n = blockIdx.x & 63, fs = blockIdx.x >> 6;
  const int t = threadIdx.x;
#pragma unroll
  for (int p = 0; p < 4; ++p) {
    const int idx = t + 256 * p;
    const int g = idx >> 9, dd = (idx >> 6) & 7, m = idx & 63;
    const int d = g * 64 + fs * 8 + dd;
    float s = 0.f;
#pragma unroll
    for (int cc = 0; cc < CH_; ++cc)
      s += part_kv[(size_t)(cc * N_ + n) * (D2_ * D_) + d * 64 + m];
    if (g == 0) l0s[dd][m] = s; else l1s[dd][m] = s;
  }
  if (fs == 0 && t < D2_) {
    float s = 0.f;
#pragma unroll
    for (int cc = 0; cc < CH_; ++cc)
      s += part_ks[(size_t)(cc * N_ + n) * D2_ + t];
    ksb[n * D2_ + 2 * (t & 63) + (t >> 6)] = bf16u(s);
  }
  __syncthreads();
  u32* kvt32 = (u32*)(kvt + (size_t)n * (D_ * D2_));
#pragma unroll
  for (int p = 0; p < 2; ++p) {
    const int idx = t + 256 * p;
    const int j = idx & 7, m = idx >> 3;
    kvt32[m * 64 + fs * 8 + j] = pack2bf(l0s[j][m], l1s[j][m]);
  }
}

// ---------------------------------------------------------------------------
// r3_phase2 (unchanged, verified): out[l][m] = z * sum_f q_[l][f]*kvt[m][f].
// Zero LDS; A-frags from inline relu/sincos/pack of q; z via broadcast ksum
// B-tile. grid: 64 heads x 64 l-tiles.
// ---------------------------------------------------------------------------
__global__ __launch_bounds__(256, 4) void r3_phase2(
    const float* __restrict__ q, const u16* __restrict__ kvt,
    const u16* __restrict__ ksb, float* __restrict__ out) {
  const int bid = blockIdx.x;
  const int n = bid & 63, lt = bid >> 6;
  const int b = n >> 4, h = n & 15;
  const int t = threadIdx.x;
  const int wv = t >> 6, lane = t & 63;
  const int c_lo = lane & 15, quad = lane >> 4;
  const int l = lt * 64 + wv * 16 + c_lo;
  const float ang = (float)(l + 1) * ANGSC;
  const float sn = __sinf(ang), cs = __cosf(ang);
  const float* qrow = q + (size_t)(b * L_ + l) * E_ + h * 64;
  short8 af[4];
#pragma unroll
  for (int kk = 0; kk < 4; ++kk) {
    const float4 qv = *(const float4*)(qrow + kk * 16 + quad * 4);
    const float x = fmaxf(qv.x, 0.f), y = fmaxf(qv.y, 0.f);
    const float z2 = fmaxf(qv.z, 0.f), w = fmaxf(qv.w, 0.f);
    short8 a;
    a[0] = (short)bf16u(x * sn); a[1] = (short)bf16u(x * cs);
    a[2] = (short)bf16u(y * sn); a[3] = (short)bf16u(y * cs);
    a[4] = (short)bf16u(z2 * sn); a[5] = (short)bf16u(z2 * cs);
    a[6] = (short)bf16u(w * sn); a[7] = (short)bf16u(w * cs);
    af[kk] = a;
  }
  const u16* kvh = kvt + (size_t)n * (D_ * D2_);
  const u16* ksh = ksb + n * D2_;
  f32x4 acc[4], acc5 = (f32x4)0.f;
#pragma unroll
  for (int mt = 0; mt < 4; ++mt) acc[mt] = (f32x4)0.f;
#pragma unroll
  for (int kk = 0; kk < 4; ++kk) {
    const int fo = kk * 32 + quad * 8;
#pragma unroll
    for (int mt = 0; mt < 4; ++mt) {
      const short8 bfr = *(const short8*)&kvh[(mt * 16 + c_lo) * D2_ + fo];
      acc[mt] = __builtin_amdgcn_mfma_f32_16x16x32_bf16(af[kk], bfr, acc[mt], 0, 0, 0);
    }
    const short8 bks = *(const short8*)&ksh[fo];
    acc5 = __builtin_amdgcn_mfma_f32_16x16x32_bf16(af[kk], bks, acc5, 0, 0, 0);
  }
#pragma unroll
  for (int r = 0; r < 4; ++r) {
    const float den = __shfl(acc5[r], quad * 16);
    const float zz = 1.f / fmaxf(den, EPS_);
    const int gl = lt * 64 + wv * 16 + quad * 4 + r;
    float* ob = out + (size_t)n * (L_ * D_) + (size_t)gl * D_;
#pragma unroll
    for (int mt = 0; mt < 4; ++mt) ob[mt * 16 + c_lo] = acc[mt][r] * zz;
  }
}

// ---------------------------------------------------------------------------
extern "C" void kernel_launch(void* const* d_in, const int* in_sizes, int n_in,
                              void* d_out, int out_size, void* d_ws,
                              size_t ws_size, hipStream_t stream) {
  const float* q = (const float*)d_in[0];
  const float* k = (const float*)d_in[1];
  const float* v = (const float*)d_in[2];
  const float* mask = (const float*)d_in[3];
  float* out = (float*)d_out;

  float* part_kv = (float*)d_ws;                            // 32 MB
  float* part_ks = part_kv + (size_t)CH_ * N_ * D2_ * D_;   // 512 KB
  u16* kvt = (u16*)(part_ks + (size_t)CH_ * N_ * D2_);      // 1 MB
  u16* ksb = kvt + (size_t)N_ * D2_ * D_;                   // 16 KB

  p1f<<<dim3(CH_ * N_), dim3(256), 0, stream>>>(k, v, mask, part_kv, part_ks);
  r3_reduce<<<dim3(8 * N_), dim3(256), 0, stream>>>(part_kv, part_ks, kvt, ksb);
  r3_phase2<<<dim3(N_ * 64), dim3(256), 0, stream>>>(q, kvt, ksb, out);
}